// Round 10
// baseline (231.374 us; speedup 1.0000x reference)
//
#include <hip/hip_runtime.h>

#define Bsz 1024
#define Nn 256
#define Fdim 8
#define Eedge 1024
#define OUTC 128
#define CADV 192
#define CTOT 256
#define Ktot 32768   // Nn * OUTC
#define ASTR 40      // LDS row stride in bf16 (32+8): 16B-aligned, 2-way banks (free)

typedef __attribute__((ext_vector_type(8))) short short8;
typedef __attribute__((ext_vector_type(4))) float float4v;

static __device__ inline unsigned short f2bf(float f) {
  union { float f; unsigned u; } v; v.f = f;
  unsigned r = v.u + 0x7FFFu + ((v.u >> 16) & 1u);  // round-nearest-even
  return (unsigned short)(r >> 16);
}
static __device__ inline uint4 pack8(const unsigned short* b) {
  uint4 v;
  v.x = (unsigned)b[0] | ((unsigned)b[1] << 16);
  v.y = (unsigned)b[2] | ((unsigned)b[3] << 16);
  v.z = (unsigned)b[4] | ((unsigned)b[5] << 16);
  v.w = (unsigned)b[6] | ((unsigned)b[7] << 16);
  return v;
}

// ---------------------------------------------------------------------------
// Prep (one dispatch, 1025 blocks):
//   bid <1024 : Wt[kt][c][32] bf16 transpose (LDS-staged, coalesced flush)
//   1024      : theta + scatter S + msg. msg loop: o = t&127 is FIXED per
//               thread -> theta row hoisted to regs; S reads are LDS
//               broadcasts; stores coalesced. (R9's 25-us serial tail fix.)
// ---------------------------------------------------------------------------
__global__ __launch_bounds__(256) void prep_kernel(
    const float* __restrict__ advw, const float* __restrict__ v1w,
    const float* __restrict__ w1, const float* __restrict__ b1,
    const float* __restrict__ w2, const float* __restrict__ b2,
    const float* __restrict__ x, const int* __restrict__ ei,
    unsigned short* __restrict__ wt, float* __restrict__ msg)
{
  int bid = blockIdx.x, t = threadIdx.x;
  if (bid < 1024) {
    __shared__ unsigned short st[CTOT * ASTR];  // 20 KB
    int kt = bid, c = t;
    const float* src; int stride, col;
    if (c < CADV) { src = advw; stride = CADV; col = c; }
    else          { src = v1w;  stride = 64;   col = c - CADV; }
    for (int p = 0; p < 4; ++p) {
      unsigned short buf[8];
#pragma unroll
      for (int i = 0; i < 8; ++i)
        buf[i] = f2bf(src[(size_t)(kt * 32 + p * 8 + i) * stride + col]);
      *(uint4*)(st + c * ASTR + p * 8) = pack8(buf);
    }
    __syncthreads();
    uint4* dst = (uint4*)(wt + (size_t)kt * (CTOT * 32));
    for (int r = 0; r < 4; ++r) {
      int s = r * 256 + c;        // lane-consecutive -> coalesced
      dst[s] = *(const uint4*)(st + (s >> 2) * ASTR + (s & 3) * 8);
    }
  } else {
    __shared__ float h_s[64];
    __shared__ float theta_s[1024];
    __shared__ float S_s[Nn * Fdim];
    __shared__ int is64_s;
    if (t < 64) h_s[t] = fmaxf(w1[t] + b1[t], 0.f);
    for (int i = t; i < Nn * Fdim; i += 256) S_s[i] = 0.f;
    if (t == 0) {
      int z = 0;
      for (int i = 1; i < 16; i += 2) z |= ei[i];
      is64_s = (z == 0);  // little-endian int64 detection
    }
    __syncthreads();
    int is64 = is64_s;
    for (int i = 0; i < 4; ++i) {
      int c = t + i * 256;
      float acc = b2[c];
#pragma unroll
      for (int j = 0; j < 64; ++j) acc += h_s[j] * w2[j * 1024 + c];
      theta_s[c] = acc;
    }
    for (int e = t; e < Eedge; e += 256) {
      int src, tgt;
      if (is64) { src = ei[2 * e]; tgt = ei[2 * (Eedge + e)]; }
      else      { src = ei[e];     tgt = ei[Eedge + e]; }
      src &= 255; tgt &= 255;
#pragma unroll
      for (int f = 0; f < Fdim; ++f)
        atomicAdd(&S_s[tgt * Fdim + f], x[src * Fdim + f]);
    }
    __syncthreads();
    // msg[n][o] = sum_f S[n][f] * theta[f][o]; idx = i*256+t -> o = t&127 fixed
    float th[8];
#pragma unroll
    for (int f = 0; f < Fdim; ++f) th[f] = theta_s[f * 128 + (t & 127)];
    int half = t >> 7;
#pragma unroll 4
    for (int i = 0; i < 128; ++i) {
      int n = 2 * i + half;
      float m = 0.f;
#pragma unroll
      for (int f = 0; f < Fdim; ++f) m += S_s[n * Fdim + f] * th[f];
      msg[i * 256 + t] = m;   // coalesced 1 KB/iter
    }
  }
}

// ---------------------------------------------------------------------------
// feat bf16 -> feat[kt][b][32], NO LDS / NO syncthreads (R9, unchanged).
// Wave = 4 batch rows x 16 o-pieces; rootw slice register-cached; one uint4
// store per node per lane (dwordx4 class -> no write amp).
// ---------------------------------------------------------------------------
__global__ __launch_bounds__(256, 3) void feat_kernel(
    const float* __restrict__ x, const float* __restrict__ rootw,
    const float* __restrict__ convb, const float* __restrict__ msgg,
    unsigned short* __restrict__ feat)
{
  int t = threadIdx.x;
  int wave = t >> 6, lane = t & 63;
  int br = lane >> 4, pc = lane & 15;
  int b = blockIdx.x * 16 + wave * 4 + br;
  int n0 = blockIdx.y * 32;

  float rw[8][8], cb[8];
#pragma unroll
  for (int f = 0; f < 8; ++f) {
    float4 r0 = *(const float4*)(rootw + f * OUTC + pc * 8);
    float4 r1 = *(const float4*)(rootw + f * OUTC + pc * 8 + 4);
    rw[f][0] = r0.x; rw[f][1] = r0.y; rw[f][2] = r0.z; rw[f][3] = r0.w;
    rw[f][4] = r1.x; rw[f][5] = r1.y; rw[f][6] = r1.z; rw[f][7] = r1.w;
  }
  {
    float4 c0 = *(const float4*)(convb + pc * 8);
    float4 c1 = *(const float4*)(convb + pc * 8 + 4);
    cb[0] = c0.x; cb[1] = c0.y; cb[2] = c0.z; cb[3] = c0.w;
    cb[4] = c1.x; cb[5] = c1.y; cb[6] = c1.z; cb[7] = c1.w;
  }
  bool isb0 = (b == 0);

  for (int nn = 0; nn < 32; ++nn) {
    int node = n0 + nn;
    const float* xp = x + ((size_t)b * Nn + node) * Fdim;
    float4 xa = *(const float4*)xp;
    float4 xb = *(const float4*)(xp + 4);
    float xv[8] = {xa.x, xa.y, xa.z, xa.w, xb.x, xb.y, xb.z, xb.w};
    float z[8];
#pragma unroll
    for (int j = 0; j < 8; ++j) z[j] = cb[j];
#pragma unroll
    for (int f = 0; f < 8; ++f)
#pragma unroll
      for (int j = 0; j < 8; ++j) z[j] += xv[f] * rw[f][j];
    if (isb0) {
      float4 m0 = *(const float4*)(msgg + node * OUTC + pc * 8);
      float4 m1 = *(const float4*)(msgg + node * OUTC + pc * 8 + 4);
      z[0] += m0.x; z[1] += m0.y; z[2] += m0.z; z[3] += m0.w;
      z[4] += m1.x; z[5] += m1.y; z[6] += m1.z; z[7] += m1.w;
    }
    unsigned short buf[8];
#pragma unroll
    for (int j = 0; j < 8; ++j) buf[j] = f2bf(fmaxf(z[j], 0.f));
    int kt = node * 4 + (pc >> 2);
    *(uint4*)(feat + ((size_t)kt * Bsz + b) * 32 + (pc & 3) * 8) = pack8(buf);
  }
}

// ---------------------------------------------------------------------------
// MFMA GEMM with single-barrier LDS double-buffer:
//   iter kk: write buf[kk&1] from regs (vmcnt overlapped with prior MFMA);
//            issue loads kk+1; ONE barrier; MFMA from buf[kk&1].
// WAR on buf[kk&1] (read at iter kk-2) is covered by iter kk-1's barrier.
// Tile 128m x 256c, 8 waves, wave 64x64; operands swapped (mfma(bF,aF)) so
// epilogue is per-lane dwordx4 (no write amp — R8/R9 verified). LDS 60 KB.
// ---------------------------------------------------------------------------
__global__ __launch_bounds__(512, 2) void gemm_mfma(
    const unsigned short* __restrict__ feat, const unsigned short* __restrict__ wt,
    float* __restrict__ part, int iters)
{
  __shared__ short a_s[2][128 * ASTR];   // 2 x 10 KB
  __shared__ short b_s[2][256 * ASTR];   // 2 x 20 KB
  int t = threadIdx.x;
  int mb = blockIdx.x;   // 0..7
  int ch = blockIdx.y;   // K chunk
  int wave = t >> 6, lane = t & 63;
  int wm = wave >> 2, wn = wave & 3;   // 2 x 4 wave grid
  int lm = lane & 15, lq = lane >> 4;

  float4v acc[4][4];   // [i: m-tile][j: c-tile]; reg r -> c = j*16 + lq*4 + r
#pragma unroll
  for (int i = 0; i < 4; ++i)
#pragma unroll
    for (int j = 0; j < 4; ++j) acc[i][j] = (float4v)0.f;

  int kt0 = ch * iters;
  int wr0 = (t >> 2) * ASTR + (t & 3) * 8;
  int u1 = t + 512;
  int wr1 = (u1 >> 2) * ASTR + (u1 & 3) * 8;

  // preload tile 0
  const uint4* gB = (const uint4*)wt + (size_t)kt0 * 1024;
  const uint4* gA = (const uint4*)feat + (size_t)kt0 * 4096 + mb * 512;
  uint4 vb0 = gB[t], vb1 = gB[t + 512], va = gA[t];

  for (int kk = 0; kk < iters; ++kk) {
    short* bb = b_s[kk & 1];
    short* ab = a_s[kk & 1];
    *(uint4*)(bb + wr0) = vb0;
    *(uint4*)(bb + wr1) = vb1;
    *(uint4*)(ab + wr0) = va;
    if (kk + 1 < iters) {
      const uint4* gB2 = (const uint4*)wt + (size_t)(kt0 + kk + 1) * 1024;
      const uint4* gA2 = (const uint4*)feat + (size_t)(kt0 + kk + 1) * 4096 + mb * 512;
      vb0 = gB2[t]; vb1 = gB2[t + 512]; va = gA2[t];
    }
    __syncthreads();
    short8 aF[4];
#pragma unroll
    for (int i = 0; i < 4; ++i)
      aF[i] = *(const short8*)(ab + (wm * 64 + i * 16 + lm) * ASTR + lq * 8);
#pragma unroll
    for (int j = 0; j < 4; ++j) {
      short8 bF = *(const short8*)(bb + (wn * 64 + j * 16 + lm) * ASTR + lq * 8);
#pragma unroll
      for (int i = 0; i < 4; ++i)
        acc[i][j] = __builtin_amdgcn_mfma_f32_16x16x32_bf16(bF, aF[i], acc[i][j], 0, 0, 0);
    }
  }

  // epilogue: per-lane dwordx4 (lanes lq 0..3 cover contiguous 64 B)
  float* pb = part + ((size_t)ch * Bsz + mb * 128) * CTOT;
#pragma unroll
  for (int i = 0; i < 4; ++i) {
    int m = wm * 64 + i * 16 + lm;
#pragma unroll
    for (int j = 0; j < 4; ++j) {
      int c = wn * 64 + j * 16 + lq * 4;
      *(float4v*)(pb + (size_t)m * CTOT + c) = acc[i][j];
    }
  }
}

// ---------------------------------------------------------------------------
// Final: reduce fp32 split-K partials, biases+relu, val MLP, dueling combine.
// ---------------------------------------------------------------------------
__global__ __launch_bounds__(256) void final_kernel(
    const float* __restrict__ part, int ns,
    const float* __restrict__ advb, const float* __restrict__ v1b,
    const float* __restrict__ v2w, const float* __restrict__ v2b,
    const float* __restrict__ v3w, const float* __restrict__ v3b,
    float* __restrict__ out)
{
  __shared__ float adv_s[CADV];
  __shared__ float v1_s[64];
  __shared__ float val2_s[64];
  __shared__ float val3_s[64];
  int b = blockIdx.x, t = threadIdx.x;
  float s = 0.f;
  const float* p = part + (size_t)b * CTOT + t;
  for (int i = 0; i < ns; ++i) s += p[(size_t)i * Bsz * CTOT];
  if (t < CADV) adv_s[t] = fmaxf(s + advb[t], 0.f);
  else          v1_s[t - CADV] = fmaxf(s + v1b[t - CADV], 0.f);
  __syncthreads();
  if (t < 64) {
    float a = v2b[t];
#pragma unroll
    for (int i = 0; i < 64; ++i) a += v1_s[i] * v2w[i * 64 + t];
    val2_s[t] = fmaxf(a, 0.f);
  }
  __syncthreads();
  if (t < 64) {
    float a = v3b[t];
#pragma unroll
    for (int j = 0; j < 64; ++j) a += val2_s[j] * v3w[j * 64 + t];
    val3_s[t] = a;
  }
  __syncthreads();
  if (t < CADV) {
    int d = t / 3;
    float mean = (adv_s[d * 3] + adv_s[d * 3 + 1] + adv_s[d * 3 + 2]) * (1.f / 3.f);
    out[(size_t)b * CADV + t] = val3_s[d] + adv_s[t] - mean;
  }
}

extern "C" void kernel_launch(void* const* d_in, const int* in_sizes, int n_in,
                              void* d_out, int out_size, void* d_ws, size_t ws_size,
                              hipStream_t stream)
{
  (void)in_sizes; (void)n_in; (void)out_size;
  const float* x     = (const float*)d_in[0];
  const int*   ei    = (const int*)d_in[1];
  const float* w1    = (const float*)d_in[2];
  const float* b1    = (const float*)d_in[3];
  const float* w2    = (const float*)d_in[4];
  const float* b2    = (const float*)d_in[5];
  const float* rootw = (const float*)d_in[6];
  const float* convb = (const float*)d_in[7];
  const float* advw  = (const float*)d_in[8];
  const float* advb  = (const float*)d_in[9];
  const float* v1w   = (const float*)d_in[10];
  const float* v1b   = (const float*)d_in[11];
  const float* v2w   = (const float*)d_in[12];
  const float* v2b   = (const float*)d_in[13];
  const float* v3w   = (const float*)d_in[14];
  const float* v3b   = (const float*)d_in[15];
  float* out = (float*)d_out;

  const size_t msgB  = 131072;                         // msg 128 KB
  const size_t wtB   = (size_t)Ktot * CTOT * 2;        // 16.8 MB
  const size_t featB = (size_t)Bsz * Ktot * 2;         // 67 MB

  int NS = 64;   // proven: ws >= 148 MB (R3..R9 footprints ran)
  while (NS > 8 && msgB + wtB + featB + (size_t)NS * Bsz * CTOT * 4 > ws_size)
    NS >>= 1;

  float* msg = (float*)d_ws;
  unsigned short* wtp   = (unsigned short*)((char*)d_ws + msgB);
  unsigned short* featp = (unsigned short*)((char*)d_ws + msgB + wtB);
  float* part = (float*)((char*)d_ws + msgB + wtB + featB);

  prep_kernel<<<1025, 256, 0, stream>>>(advw, v1w, w1, b1, w2, b2, x, ei,
                                        wtp, msg);
  feat_kernel<<<dim3(Bsz / 16, 8), 256, 0, stream>>>(x, rootw, convb, msg, featp);
  gemm_mfma<<<dim3(8, NS), 512, 0, stream>>>(featp, wtp, part, 1024 / NS);
  final_kernel<<<Bsz, 256, 0, stream>>>(part, NS, advb, v1b, v2w, v2b, v3w, v3b, out);
}

// Round 11
// 209.428 us; speedup vs baseline: 1.1048x; 1.1048x over previous
//
#include <hip/hip_runtime.h>

#define Bsz 1024
#define Nn 256
#define Fdim 8
#define Eedge 1024
#define OUTC 128
#define CADV 192
#define CTOT 256
#define Ktot 32768   // Nn * OUTC
#define ASTR 40      // LDS row stride in bf16 (32+8): 16B-aligned, 2-way banks (free)

typedef __attribute__((ext_vector_type(8))) short short8;
typedef __attribute__((ext_vector_type(4))) float float4v;

static __device__ inline unsigned short f2bf(float f) {
  union { float f; unsigned u; } v; v.f = f;
  unsigned r = v.u + 0x7FFFu + ((v.u >> 16) & 1u);  // round-nearest-even
  return (unsigned short)(r >> 16);
}
static __device__ inline uint4 pack8(const unsigned short* b) {
  uint4 v;
  v.x = (unsigned)b[0] | ((unsigned)b[1] << 16);
  v.y = (unsigned)b[2] | ((unsigned)b[3] << 16);
  v.z = (unsigned)b[4] | ((unsigned)b[5] << 16);
  v.w = (unsigned)b[6] | ((unsigned)b[7] << 16);
  return v;
}

// ---------------------------------------------------------------------------
// K1: fused prep + feat, ONE dispatch (1537 blocks) so the serial tail
// (theta/scatter) overlaps the wide feat/wt work instead of running alone
// (R10: tail straggler made prep 52.7 us at 5% occupancy).
//   block 0       : theta + scatter S + corrected bf16 feat row b=0 -> feat0
//   blocks 1..512 : feat WITHOUT msg for all batches (b=0 fixed in K2)
//   blocks 513..  : Wt[kt][c][32] bf16 transpose (LDS-staged, coalesced)
// ---------------------------------------------------------------------------
__global__ __launch_bounds__(256) void prep_feat_kernel(
    const float* __restrict__ x, const int* __restrict__ ei,
    const float* __restrict__ w1, const float* __restrict__ b1,
    const float* __restrict__ w2, const float* __restrict__ b2,
    const float* __restrict__ rootw, const float* __restrict__ convb,
    const float* __restrict__ advw, const float* __restrict__ v1w,
    unsigned short* __restrict__ wt, unsigned short* __restrict__ feat,
    unsigned short* __restrict__ feat0)
{
  __shared__ __align__(16) char smem[20480];
  int bid = blockIdx.x, t = threadIdx.x;

  if (bid == 0) {
    // ---- tail: theta (edge-MLP, identical per edge), scatter S, feat0 ----
    float* h_s  = (float*)smem;          // 64
    float* th_s = h_s + 64;              // 1024
    float* S_s  = th_s + 1024;           // 2048  (ends at 12544 B)
    int*   flag = (int*)(S_s + 2048);
    if (t < 64) h_s[t] = fmaxf(w1[t] + b1[t], 0.f);
    for (int i = t; i < Nn * Fdim; i += 256) S_s[i] = 0.f;
    if (t == 0) {
      int z = 0;
      for (int i = 1; i < 16; i += 2) z |= ei[i];
      *flag = (z == 0);  // little-endian int64 detection
    }
    __syncthreads();
    int is64 = *flag;
    for (int i = 0; i < 4; ++i) {
      int c = t + i * 256;
      float acc = b2[c];
#pragma unroll
      for (int j = 0; j < 64; ++j) acc += h_s[j] * w2[j * 1024 + c];
      th_s[c] = acc;
    }
    // scatter: prefetch all edge indices first (kills the ei->x pointer chase)
    int srcs[4], tgts[4];
#pragma unroll
    for (int q = 0; q < 4; ++q) {
      int e = t + q * 256;
      if (is64) { srcs[q] = ei[2 * e]; tgts[q] = ei[2 * (Eedge + e)]; }
      else      { srcs[q] = ei[e];     tgts[q] = ei[Eedge + e]; }
      srcs[q] &= 255; tgts[q] &= 255;
    }
#pragma unroll
    for (int q = 0; q < 4; ++q) {
      const float* xp = x + srcs[q] * Fdim;
#pragma unroll
      for (int f = 0; f < Fdim; ++f)
        atomicAdd(&S_s[tgts[q] * Fdim + f], xp[f]);
    }
    __syncthreads();
    // feat0[n*128+o] = relu(x[0,n,:]@rootw[:,o] + convb[o] + S[n,:]@theta[:,o])
    int o = t & 127, half = t >> 7;
    float th[8], rwv[8];
#pragma unroll
    for (int f = 0; f < Fdim; ++f) {
      th[f]  = th_s[f * 128 + o];
      rwv[f] = rootw[f * OUTC + o];
    }
    float cbv = convb[o];
#pragma unroll 4
    for (int i = 0; i < 128; ++i) {
      int n = 2 * i + half;
      const float* xp = x + n * Fdim;   // batch 0 rows: 8 KB region, L1-hot
      float v = cbv, m = 0.f;
#pragma unroll
      for (int f = 0; f < Fdim; ++f) {
        v += xp[f] * rwv[f];
        m += S_s[n * Fdim + f] * th[f];
      }
      feat0[i * 256 + t] = f2bf(fmaxf(v + m, 0.f));  // coalesced (== n*128+o)
    }
  } else if (bid <= 512) {
    // ---- feat: wave = 4 batch rows x 16 o-pieces, register rootw slice ----
    int u = bid - 1;
    int wave = t >> 6, lane = t & 63;
    int br = lane >> 4, pc = lane & 15;
    int b = (u & 63) * 16 + wave * 4 + br;
    int n0 = (u >> 6) * 32;
    float rw[8][8], cb[8];
#pragma unroll
    for (int f = 0; f < 8; ++f) {
      float4 r0 = *(const float4*)(rootw + f * OUTC + pc * 8);
      float4 r1 = *(const float4*)(rootw + f * OUTC + pc * 8 + 4);
      rw[f][0] = r0.x; rw[f][1] = r0.y; rw[f][2] = r0.z; rw[f][3] = r0.w;
      rw[f][4] = r1.x; rw[f][5] = r1.y; rw[f][6] = r1.z; rw[f][7] = r1.w;
    }
    {
      float4 c0 = *(const float4*)(convb + pc * 8);
      float4 c1 = *(const float4*)(convb + pc * 8 + 4);
      cb[0] = c0.x; cb[1] = c0.y; cb[2] = c0.z; cb[3] = c0.w;
      cb[4] = c1.x; cb[5] = c1.y; cb[6] = c1.z; cb[7] = c1.w;
    }
    for (int nn = 0; nn < 32; ++nn) {
      int node = n0 + nn;
      const float* xp = x + ((size_t)b * Nn + node) * Fdim;
      float4 xa = *(const float4*)xp;
      float4 xb = *(const float4*)(xp + 4);
      float xv[8] = {xa.x, xa.y, xa.z, xa.w, xb.x, xb.y, xb.z, xb.w};
      float z[8];
#pragma unroll
      for (int j = 0; j < 8; ++j) z[j] = cb[j];
#pragma unroll
      for (int f = 0; f < 8; ++f)
#pragma unroll
        for (int j = 0; j < 8; ++j) z[j] += xv[f] * rw[f][j];
      unsigned short buf[8];
#pragma unroll
      for (int j = 0; j < 8; ++j) buf[j] = f2bf(fmaxf(z[j], 0.f));
      int kt = node * 4 + (pc >> 2);
      *(uint4*)(feat + ((size_t)kt * Bsz + b) * 32 + (pc & 3) * 8) = pack8(buf);
    }
  } else {
    // ---- wt transpose: LDS-staged, coalesced flush ----
    unsigned short* st = (unsigned short*)smem;  // 20 KB
    int kt = bid - 513, c = t;
    const float* src; int stride, col;
    if (c < CADV) { src = advw; stride = CADV; col = c; }
    else          { src = v1w;  stride = 64;   col = c - CADV; }
    for (int p = 0; p < 4; ++p) {
      unsigned short buf[8];
#pragma unroll
      for (int i = 0; i < 8; ++i)
        buf[i] = f2bf(src[(size_t)(kt * 32 + p * 8 + i) * stride + col]);
      *(uint4*)(st + c * ASTR + p * 8) = pack8(buf);
    }
    __syncthreads();
    uint4* dst = (uint4*)(wt + (size_t)kt * (CTOT * 32));
    for (int r = 0; r < 4; ++r) {
      int s = r * 256 + c;        // lane-consecutive -> coalesced
      dst[s] = *(const uint4*)(st + (s >> 2) * ASTR + (s & 3) * 8);
    }
  }
}

// ---------------------------------------------------------------------------
// K2: MFMA GEMM, single-barrier LDS double-buffer (R10) + b=0 row override:
// mb==0 blocks replace A-row 0 from feat0 (correct msg-augmented values)
// during staging — 4 extra uint4 loads per iter for 4/512 threads.
// Operands swapped (mfma(bF,aF)) -> per-lane dwordx4 epilogue (no write amp).
// ---------------------------------------------------------------------------
__global__ __launch_bounds__(512, 2) void gemm_mfma(
    const unsigned short* __restrict__ feat, const unsigned short* __restrict__ wt,
    const unsigned short* __restrict__ feat0, float* __restrict__ part, int iters)
{
  __shared__ short a_s[2][128 * ASTR];   // 2 x 10 KB
  __shared__ short b_s[2][256 * ASTR];   // 2 x 20 KB
  int t = threadIdx.x;
  int mb = blockIdx.x;   // 0..7
  int ch = blockIdx.y;   // K chunk
  int wave = t >> 6, lane = t & 63;
  int wm = wave >> 2, wn = wave & 3;   // 2 x 4 wave grid
  int lm = lane & 15, lq = lane >> 4;

  float4v acc[4][4];   // [i: m-tile][j: c-tile]; reg r -> c = j*16 + lq*4 + r
#pragma unroll
  for (int i = 0; i < 4; ++i)
#pragma unroll
    for (int j = 0; j < 4; ++j) acc[i][j] = (float4v)0.f;

  int kt0 = ch * iters;
  int wr0 = (t >> 2) * ASTR + (t & 3) * 8;
  int u1 = t + 512;
  int wr1 = (u1 >> 2) * ASTR + (u1 & 3) * 8;
  bool fix = (mb == 0) && (t < 4);
  const uint4* f0q = (const uint4*)feat0;

  // preload tile 0
  const uint4* gB = (const uint4*)wt + (size_t)kt0 * 1024;
  const uint4* gA = (const uint4*)feat + (size_t)kt0 * 4096 + mb * 512;
  uint4 vb0 = gB[t], vb1 = gB[t + 512], va = gA[t];
  if (fix) va = f0q[kt0 * 4 + t];

  for (int kk = 0; kk < iters; ++kk) {
    short* bb = b_s[kk & 1];
    short* ab = a_s[kk & 1];
    *(uint4*)(bb + wr0) = vb0;
    *(uint4*)(bb + wr1) = vb1;
    *(uint4*)(ab + wr0) = va;
    if (kk + 1 < iters) {
      const uint4* gB2 = (const uint4*)wt + (size_t)(kt0 + kk + 1) * 1024;
      const uint4* gA2 = (const uint4*)feat + (size_t)(kt0 + kk + 1) * 4096 + mb * 512;
      vb0 = gB2[t]; vb1 = gB2[t + 512]; va = gA2[t];
      if (fix) va = f0q[(kt0 + kk + 1) * 4 + t];
    }
    __syncthreads();
    short8 aF[4];
#pragma unroll
    for (int i = 0; i < 4; ++i)
      aF[i] = *(const short8*)(ab + (wm * 64 + i * 16 + lm) * ASTR + lq * 8);
#pragma unroll
    for (int j = 0; j < 4; ++j) {
      short8 bF = *(const short8*)(bb + (wn * 64 + j * 16 + lm) * ASTR + lq * 8);
#pragma unroll
      for (int i = 0; i < 4; ++i)
        acc[i][j] = __builtin_amdgcn_mfma_f32_16x16x32_bf16(bF, aF[i], acc[i][j], 0, 0, 0);
    }
  }

  // epilogue: per-lane dwordx4 (lanes lq 0..3 cover contiguous 64 B)
  float* pb = part + ((size_t)ch * Bsz + mb * 128) * CTOT;
#pragma unroll
  for (int i = 0; i < 4; ++i) {
    int m = wm * 64 + i * 16 + lm;
#pragma unroll
    for (int j = 0; j < 4; ++j) {
      int c = wn * 64 + j * 16 + lq * 4;
      *(float4v*)(pb + (size_t)m * CTOT + c) = acc[i][j];
    }
  }
}

// ---------------------------------------------------------------------------
// K3: reduce fp32 split-K partials, biases+relu, val MLP, dueling combine.
// ---------------------------------------------------------------------------
__global__ __launch_bounds__(256) void final_kernel(
    const float* __restrict__ part, int ns,
    const float* __restrict__ advb, const float* __restrict__ v1b,
    const float* __restrict__ v2w, const float* __restrict__ v2b,
    const float* __restrict__ v3w, const float* __restrict__ v3b,
    float* __restrict__ out)
{
  __shared__ float adv_s[CADV];
  __shared__ float v1_s[64];
  __shared__ float val2_s[64];
  __shared__ float val3_s[64];
  int b = blockIdx.x, t = threadIdx.x;
  float s = 0.f;
  const float* p = part + (size_t)b * CTOT + t;
  for (int i = 0; i < ns; ++i) s += p[(size_t)i * Bsz * CTOT];
  if (t < CADV) adv_s[t] = fmaxf(s + advb[t], 0.f);
  else          v1_s[t - CADV] = fmaxf(s + v1b[t - CADV], 0.f);
  __syncthreads();
  if (t < 64) {
    float a = v2b[t];
#pragma unroll
    for (int i = 0; i < 64; ++i) a += v1_s[i] * v2w[i * 64 + t];
    val2_s[t] = fmaxf(a, 0.f);
  }
  __syncthreads();
  if (t < 64) {
    float a = v3b[t];
#pragma unroll
    for (int j = 0; j < 64; ++j) a += val2_s[j] * v3w[j * 64 + t];
    val3_s[t] = a;
  }
  __syncthreads();
  if (t < CADV) {
    int d = t / 3;
    float mean = (adv_s[d * 3] + adv_s[d * 3 + 1] + adv_s[d * 3 + 2]) * (1.f / 3.f);
    out[(size_t)b * CADV + t] = val3_s[d] + adv_s[t] - mean;
  }
}

extern "C" void kernel_launch(void* const* d_in, const int* in_sizes, int n_in,
                              void* d_out, int out_size, void* d_ws, size_t ws_size,
                              hipStream_t stream)
{
  (void)in_sizes; (void)n_in; (void)out_size;
  const float* x     = (const float*)d_in[0];
  const int*   ei    = (const int*)d_in[1];
  const float* w1    = (const float*)d_in[2];
  const float* b1    = (const float*)d_in[3];
  const float* w2    = (const float*)d_in[4];
  const float* b2    = (const float*)d_in[5];
  const float* rootw = (const float*)d_in[6];
  const float* convb = (const float*)d_in[7];
  const float* advw  = (const float*)d_in[8];
  const float* advb  = (const float*)d_in[9];
  const float* v1w   = (const float*)d_in[10];
  const float* v1b   = (const float*)d_in[11];
  const float* v2w   = (const float*)d_in[12];
  const float* v2b   = (const float*)d_in[13];
  const float* v3w   = (const float*)d_in[14];
  const float* v3b   = (const float*)d_in[15];
  float* out = (float*)d_out;

  const size_t f0B   = 131072;                         // feat0 64 KB (padded)
  const size_t wtB   = (size_t)Ktot * CTOT * 2;        // 16.8 MB
  const size_t featB = (size_t)Bsz * Ktot * 2;         // 67 MB

  int NS = 64;   // proven: ws >= 148 MB (R3..R10 footprints ran)
  while (NS > 8 && f0B + wtB + featB + (size_t)NS * Bsz * CTOT * 4 > ws_size)
    NS >>= 1;

  unsigned short* feat0 = (unsigned short*)d_ws;
  unsigned short* wtp   = (unsigned short*)((char*)d_ws + f0B);
  unsigned short* featp = (unsigned short*)((char*)d_ws + f0B + wtB);
  float* part = (float*)((char*)d_ws + f0B + wtB + featB);

  prep_feat_kernel<<<1537, 256, 0, stream>>>(x, ei, w1, b1, w2, b2, rootw,
                                             convb, advw, v1w, wtp, featp, feat0);
  gemm_mfma<<<dim3(8, NS), 512, 0, stream>>>(featp, wtp, feat0, part, 1024 / NS);
  final_kernel<<<Bsz, 256, 0, stream>>>(part, NS, advb, v1b, v2w, v2b, v3w, v3b, out);
}